// Round 1
// baseline (152.807 us; speedup 1.0000x reference)
//
#include <hip/hip_runtime.h>

#define BLOCK 256

// Kernel 1: one block per basis row b.
// Computes R[b] = sum_c |weights[b,c]|, writes scale[b] = W[b] / R[b].
__global__ __launch_bounds__(BLOCK) void rowscale_kernel(
    const float* __restrict__ weights, const float* __restrict__ W,
    float* __restrict__ scale, int B, int C) {
  int b = blockIdx.x;
  if (b >= B) return;
  const float* row = weights + (size_t)b * (size_t)C;
  int n4 = C >> 2;
  float acc = 0.f;
  if ((C & 3) == 0) {
    const float4* row4 = reinterpret_cast<const float4*>(row);
    for (int i = threadIdx.x; i < n4; i += BLOCK) {
      float4 v = row4[i];
      acc += fabsf(v.x) + fabsf(v.y) + fabsf(v.z) + fabsf(v.w);
    }
  } else {
    for (int c = threadIdx.x; c < C; c += BLOCK) acc += fabsf(row[c]);
  }
  // wave (64-lane) reduction
  for (int off = 32; off > 0; off >>= 1)
    acc += __shfl_down(acc, off, 64);
  __shared__ float red[BLOCK / 64];
  int lane = threadIdx.x & 63;
  int wv = threadIdx.x >> 6;
  if (lane == 0) red[wv] = acc;
  __syncthreads();
  if (threadIdx.x == 0) {
    float total = 0.f;
    for (int w = 0; w < BLOCK / 64; ++w) total += red[w];
    scale[b] = W[b] / total;
  }
}

// Kernel 2: out[c] += sum_{b in chunk} scale[b] * |weights[b,c]|.
// grid.x covers columns in float4 units, grid.y covers b-chunks.
__global__ __launch_bounds__(BLOCK) void colsum_kernel(
    const float* __restrict__ weights, const float* __restrict__ scale,
    float* __restrict__ out, int B, int C, int bchunk) {
  int n4 = C >> 2;
  int c4 = blockIdx.x * BLOCK + threadIdx.x;
  int b0 = blockIdx.y * bchunk;
  int b1 = min(B, b0 + bchunk);

  if (c4 < n4) {
    float4 acc = make_float4(0.f, 0.f, 0.f, 0.f);
    // C % 4 == 0 in this problem (100000); rows stay 16B-aligned.
    const float4* w4 = reinterpret_cast<const float4*>(weights);
    size_t rowstride4 = (size_t)(C >> 2);
    const float4* p = w4 + (size_t)b0 * rowstride4 + c4;
#pragma unroll 4
    for (int b = b0; b < b1; ++b, p += rowstride4) {
      float4 v = *p;
      float s = scale[b];
      acc.x = fmaf(s, fabsf(v.x), acc.x);
      acc.y = fmaf(s, fabsf(v.y), acc.y);
      acc.z = fmaf(s, fabsf(v.z), acc.z);
      acc.w = fmaf(s, fabsf(v.w), acc.w);
    }
    int c = c4 << 2;
    atomicAdd(&out[c + 0], acc.x);
    atomicAdd(&out[c + 1], acc.y);
    atomicAdd(&out[c + 2], acc.z);
    atomicAdd(&out[c + 3], acc.w);
  }

  // Scalar tail for C % 4 != 0 (empty when C divisible by 4).
  int tail = n4 << 2;
  if (blockIdx.x == 0) {
    for (int c = tail + threadIdx.x; c < C; c += BLOCK) {
      float acc = 0.f;
      for (int b = b0; b < b1; ++b)
        acc = fmaf(scale[b], fabsf(weights[(size_t)b * (size_t)C + c]), acc);
      atomicAdd(&out[c], acc);
    }
  }
}

extern "C" void kernel_launch(void* const* d_in, const int* in_sizes, int n_in,
                              void* d_out, int out_size, void* d_ws, size_t ws_size,
                              hipStream_t stream) {
  const float* W = (const float*)d_in[0];
  const float* weights = (const float*)d_in[1];
  float* out = (float*)d_out;
  float* scale = (float*)d_ws;  // B floats of scratch

  int B = in_sizes[0];              // 1024
  int C = out_size;                 // 100000 (== num_classes)

  // Zero the output (poisoned to 0xAA by the harness; atomics accumulate).
  hipMemsetAsync(d_out, 0, (size_t)out_size * sizeof(float), stream);

  // Pass 1: row scales.
  rowscale_kernel<<<B, BLOCK, 0, stream>>>(weights, W, scale, B, C);

  // Pass 2: weighted column sums.
  int n4 = C >> 2;
  int colblocks = (n4 + BLOCK - 1) / BLOCK;      // 98
  if (colblocks < 1) colblocks = 1;
  const int BCHUNK = 128;
  int bchunks = (B + BCHUNK - 1) / BCHUNK;       // 8
  dim3 grid(colblocks, bchunks);
  colsum_kernel<<<grid, BLOCK, 0, stream>>>(weights, scale, out, B, C, BCHUNK);
}

// Round 2
// 150.042 us; speedup vs baseline: 1.0184x; 1.0184x over previous
//
#include <hip/hip_runtime.h>

#define BLOCK 256
#define NCHUNKS 32

// ---------------------------------------------------------------------------
// Pass 1: one block per basis row b.
// R[b] = sum_c |weights[b,c]|;  scale[b] = W[b] / R[b].
// Blocks dispatch in ascending b, so the HIGHEST rows are read LAST and
// linger in the 256 MB Infinity Cache for pass 2 (which reads descending).
// ---------------------------------------------------------------------------
__global__ __launch_bounds__(BLOCK) void rowscale_kernel(
    const float* __restrict__ weights, const float* __restrict__ W,
    float* __restrict__ scale, int B, int C) {
  int b = blockIdx.x;
  if (b >= B) return;
  const float* row = weights + (size_t)b * (size_t)C;
  int n4 = C >> 2;
  float acc = 0.f;
  if ((C & 3) == 0) {
    const float4* row4 = reinterpret_cast<const float4*>(row);
    for (int i = threadIdx.x; i < n4; i += BLOCK) {
      float4 v = row4[i];
      acc += fabsf(v.x) + fabsf(v.y) + fabsf(v.z) + fabsf(v.w);
    }
  } else {
    for (int c = threadIdx.x; c < C; c += BLOCK) acc += fabsf(row[c]);
  }
  // 64-lane wave reduction
  for (int off = 32; off > 0; off >>= 1)
    acc += __shfl_down(acc, off, 64);
  __shared__ float red[BLOCK / 64];
  int lane = threadIdx.x & 63;
  int wv = threadIdx.x >> 6;
  if (lane == 0) red[wv] = acc;
  __syncthreads();
  if (threadIdx.x == 0) {
    float total = 0.f;
    for (int w = 0; w < BLOCK / 64; ++w) total += red[w];
    scale[b] = W[b] / total;
  }
}

// ---------------------------------------------------------------------------
// Pass 2: partial weighted column sums, NO atomics.
// Chunk yc covers rows [B-(yc+1)*bchunk, B-yc*bchunk) — i.e. chunk 0 (first
// dispatched) reads the HIGHEST rows, descending, to hit what pass 1 left in
// the Infinity Cache. Each chunk writes its partial row-sums to
// partial[yc*C + c] with plain float4 stores (each element written exactly
// once -> deterministic, no memset needed).
// ---------------------------------------------------------------------------
__global__ __launch_bounds__(BLOCK) void colsum_partial_kernel(
    const float* __restrict__ weights, const float* __restrict__ scale,
    float* __restrict__ partial, int B, int C, int bchunk) {
  int n4 = C >> 2;
  int c4 = blockIdx.x * BLOCK + threadIdx.x;
  int yc = blockIdx.y;
  int bhi = B - yc * bchunk;
  int blo = bhi - bchunk;
  if (blo < 0) blo = 0;
  if (bhi <= blo) return;

  float* dst = partial + (size_t)yc * (size_t)C;

  if (c4 < n4) {
    float4 acc = make_float4(0.f, 0.f, 0.f, 0.f);
    const float4* w4 = reinterpret_cast<const float4*>(weights);
    size_t rs4 = (size_t)n4;
    const float4* p = w4 + (size_t)(bhi - 1) * rs4 + c4;
#pragma unroll 4
    for (int b = bhi - 1; b >= blo; --b, p -= rs4) {
      float4 v = *p;
      float s = scale[b];
      acc.x = fmaf(s, fabsf(v.x), acc.x);
      acc.y = fmaf(s, fabsf(v.y), acc.y);
      acc.z = fmaf(s, fabsf(v.z), acc.z);
      acc.w = fmaf(s, fabsf(v.w), acc.w);
    }
    reinterpret_cast<float4*>(dst)[c4] = acc;
  }

  // Scalar tail for C % 4 != 0 (empty for C = 100000).
  int tail = n4 << 2;
  if (blockIdx.x == 0) {
    for (int c = tail + threadIdx.x; c < C; c += BLOCK) {
      float acc = 0.f;
      for (int b = bhi - 1; b >= blo; --b)
        acc = fmaf(scale[b], fabsf(weights[(size_t)b * (size_t)C + c]), acc);
      dst[c] = acc;
    }
  }
}

// ---------------------------------------------------------------------------
// Pass 3: out[c] = sum_k partial[k*C + c]. Plain stores overwrite poison.
// ---------------------------------------------------------------------------
__global__ __launch_bounds__(BLOCK) void reduce_partials_kernel(
    const float* __restrict__ partial, float* __restrict__ out, int C,
    int nchunks) {
  int c = blockIdx.x * BLOCK + threadIdx.x;
  if (c >= C) return;
  float s = 0.f;
  for (int k = 0; k < nchunks; ++k) s += partial[(size_t)k * (size_t)C + c];
  out[c] = s;
}

extern "C" void kernel_launch(void* const* d_in, const int* in_sizes, int n_in,
                              void* d_out, int out_size, void* d_ws, size_t ws_size,
                              hipStream_t stream) {
  const float* W = (const float*)d_in[0];
  const float* weights = (const float*)d_in[1];
  float* out = (float*)d_out;

  int B = in_sizes[0];   // 1024
  int C = out_size;      // 100000

  // Workspace layout: [0,4KB) scale, [4KB, ...) partials.
  float* scale = (float*)d_ws;
  float* partial = (float*)((char*)d_ws + 4096);

  // Choose chunk count; shrink if workspace is unexpectedly small.
  int nchunks = NCHUNKS;
  while (nchunks > 1 &&
         4096 + (size_t)nchunks * (size_t)C * sizeof(float) > ws_size)
    nchunks >>= 1;
  int bchunk = (B + nchunks - 1) / nchunks;
  // Recompute effective chunk count (avoid empty chunks).
  int ychunks = (B + bchunk - 1) / bchunk;

  // Pass 1: row scales (ascending rows).
  rowscale_kernel<<<B, BLOCK, 0, stream>>>(weights, W, scale, B, C);

  // Pass 2: partial column sums (descending rows, first chunks = hottest L3).
  int n4 = C >> 2;
  int colblocks = (n4 + BLOCK - 1) / BLOCK;  // 98
  if (colblocks < 1) colblocks = 1;
  dim3 grid(colblocks, ychunks);
  colsum_partial_kernel<<<grid, BLOCK, 0, stream>>>(weights, scale, partial, B,
                                                    C, bchunk);

  // Pass 3: reduce partials into out.
  int rblocks = (C + BLOCK - 1) / BLOCK;
  reduce_partials_kernel<<<rblocks, BLOCK, 0, stream>>>(partial, out, C,
                                                        ychunks);
}